// Round 3
// baseline (360.093 us; speedup 1.0000x reference)
//
#include <hip/hip_runtime.h>

// BCEWithLogitsLoss with prefix-mask targets:
//   loss = mean_{i,j}( softplus(x[i,j]) - x[i,j] * (j < t_i) )
// Identity used:  softplus(x) - x*t = (u + |x|)/2 + log1p(exp(-|x|)),
//   where u = (t ? -x : x).  |x|-terms use free abs/-abs VOP3 modifiers.
// exp/log via __builtin_amdgcn_{exp2f,logf} (v_exp_f32 = 2^x, v_log_f32 = log2).
// Memory-bound: 256 MiB fp32 read -> ~43 us HBM floor at 6.3 TB/s.

__global__ __launch_bounds__(256) void bce_reduce_kernel(
    const float4* __restrict__ in,
    const int*    __restrict__ tgt,
    float*        __restrict__ out,
    int nvec,          // total float4 count
    int row_shift,     // log2(N/4)
    int row_mask,      // (N/4) - 1
    float inv_count)   // 1 / (B*N)
{
    const float LOG2E = 1.44269504088896340736f;

    float su = 0.f;   // sum of (t ? -x : x)
    float sa = 0.f;   // sum of |x|
    float sl = 0.f;   // sum of log2(1 + e^-|x|)

    // contiguous chunk per block, 4 float4 loads per thread-iteration
    const int per_block = nvec / gridDim.x;          // 8192 for 2048 blocks
    const int base = blockIdx.x * per_block;
    const int iters = per_block / (4 * 256);         // 8

    for (int it = 0; it < iters; ++it) {
        int i0 = base + (it * 4 + 0) * 256 + threadIdx.x;
        int i1 = base + (it * 4 + 1) * 256 + threadIdx.x;
        int i2 = base + (it * 4 + 2) * 256 + threadIdx.x;
        int i3 = base + (it * 4 + 3) * 256 + threadIdx.x;
        float4 x0 = in[i0];
        float4 x1 = in[i1];
        float4 x2 = in[i2];
        float4 x3 = in[i3];
        int t0 = tgt[i0 >> row_shift];
        int t1 = tgt[i1 >> row_shift];
        int t2 = tgt[i2 >> row_shift];
        int t3 = tgt[i3 >> row_shift];
        int c0 = (i0 & row_mask) << 2;
        int c1 = (i1 & row_mask) << 2;
        int c2 = (i2 & row_mask) << 2;
        int c3 = (i3 & row_mask) << 2;

#define ELEM(xv, cc, tt)                                                      \
        {                                                                     \
            float xe = (xv);                                                  \
            su += ((cc) < (tt)) ? -xe : xe;                                   \
            sa += fabsf(xe);                                                  \
            sl += __builtin_amdgcn_logf(                                      \
                      1.f + __builtin_amdgcn_exp2f(-fabsf(xe) * LOG2E));      \
        }

        ELEM(x0.x, c0 + 0, t0) ELEM(x0.y, c0 + 1, t0)
        ELEM(x0.z, c0 + 2, t0) ELEM(x0.w, c0 + 3, t0)
        ELEM(x1.x, c1 + 0, t1) ELEM(x1.y, c1 + 1, t1)
        ELEM(x1.z, c1 + 2, t1) ELEM(x1.w, c1 + 3, t1)
        ELEM(x2.x, c2 + 0, t2) ELEM(x2.y, c2 + 1, t2)
        ELEM(x2.z, c2 + 2, t2) ELEM(x2.w, c2 + 3, t2)
        ELEM(x3.x, c3 + 0, t3) ELEM(x3.y, c3 + 1, t3)
        ELEM(x3.z, c3 + 2, t3) ELEM(x3.w, c3 + 3, t3)
#undef ELEM
    }

    // combine: (su + sa)/2 + ln2 * sl   (sl is in log2 units)
    float acc = 0.5f * (su + sa) + 0.69314718055994530942f * sl;

    // wave64 shuffle reduction
    #pragma unroll
    for (int off = 32; off > 0; off >>= 1)
        acc += __shfl_down(acc, off, 64);

    __shared__ float wave_sums[4];
    const int lane = threadIdx.x & 63;
    const int wave = threadIdx.x >> 6;
    if (lane == 0) wave_sums[wave] = acc;
    __syncthreads();
    if (threadIdx.x == 0) {
        float b = wave_sums[0] + wave_sums[1] + wave_sums[2] + wave_sums[3];
        atomicAdd(out, b * inv_count);
    }
}

extern "C" void kernel_launch(void* const* d_in, const int* in_sizes, int n_in,
                              void* d_out, int out_size, void* d_ws, size_t ws_size,
                              hipStream_t stream) {
    const float* in  = (const float*)d_in[0];
    const int*   tgt = (const int*)d_in[1];
    float*       out = (float*)d_out;

    const long long total = (long long)in_sizes[0];   // B*N = 67108864
    const int B = in_sizes[1];                        // 8192
    const int N = (int)(total / B);                   // 8192
    const int nvec = (int)(total / 4);
    const int nvec_per_row = N / 4;                   // 2048 (pow2)
    const int row_shift = __builtin_ctz(nvec_per_row);
    const int row_mask  = nvec_per_row - 1;
    const float inv_count = 1.0f / (float)total;

    // d_out is poisoned to 0xAA before every launch; zero it for the atomic.
    (void)hipMemsetAsync(d_out, 0, sizeof(float), stream);

    const int block = 256;
    const int grid  = 2048;   // 8 blocks/CU; 512 KiB contiguous chunk per block
    bce_reduce_kernel<<<grid, block, 0, stream>>>(
        (const float4*)in, tgt, out, nvec, row_shift, row_mask, inv_count);
}